// Round 3
// baseline (203.448 us; speedup 1.0000x reference)
//
#include <hip/hip_runtime.h>
#include <hip/hip_bf16.h>

#define N_NODES 50000
#define HD 128
#define NTILES (N_NODES / 16)   // 3125, exact
#define NSLICE 16               // edge slices for privatized scatter
#define NQUART 12500            // nodes per LDS quarter (50 KB f32 bins)

using short8  = __attribute__((ext_vector_type(8))) short;   // 8 x bf16 bits
using floatx4 = __attribute__((ext_vector_type(4))) float;

__device__ __forceinline__ int pk2(float a, float b) {
#if __has_builtin(__builtin_amdgcn_cvt_pk_bf16_f32)
  typedef __bf16 bf2 __attribute__((ext_vector_type(2)));
  union { bf2 v; int i; } u;
  u.v = __builtin_amdgcn_cvt_pk_bf16_f32(a, b);
  return u.i;
#else
  union { float f; unsigned u; } x, y;
  x.f = a; y.f = b;
  unsigned lo = (x.u + 0x7fffu + ((x.u >> 16) & 1u)) >> 16;
  unsigned hi = (y.u + 0x7fffu + ((y.u >> 16) & 1u)) >> 16;
  return (int)(lo | (hi << 16));
#endif
}

__device__ __forceinline__ short f2bf(float f) {
  union { float fp; unsigned u; } un; un.fp = f;
  unsigned u = un.u + 0x7fffu + ((un.u >> 16) & 1u);   // RNE
  return (short)(u >> 16);
}

// =====================  edge phase (LDS-privatized, no device atomics) ======
// grid = 64 blocks x 1024.  slice = blk&15 (XCD-swizzled so the 4 quarter-
// blocks of a slice share an XCD's L2), quarter = blk>>4.
template <bool GATHER>
__global__ __launch_bounds__(1024) void k_scatter(
    const int* __restrict__ keys, const int* __restrict__ other,
    const float* __restrict__ dinv, float* __restrict__ partial,
    int E, int perSlice) {
  __shared__ __align__(16) float bins[NQUART];
  const int tid = threadIdx.x;
  for (int i = tid; i < NQUART / 4; i += 1024)
    ((float4*)bins)[i] = make_float4(0.f, 0.f, 0.f, 0.f);
  __syncthreads();

  const int slice = blockIdx.x & (NSLICE - 1);
  const int base  = (blockIdx.x >> 4) * NQUART;
  const int e0 = slice * perSlice;
  const int e1 = min(e0 + perSlice, E);
  for (int e = e0 + tid; e < e1; e += 1024) {
    int k = keys[e];
    if ((unsigned)(k - base) < (unsigned)NQUART) {
      float v = GATHER ? dinv[other[e]] : 1.0f;
      atomicAdd(&bins[k - base], v);           // ds_add_f32, LDS-local
    }
  }
  __syncthreads();

  float* out = partial + (size_t)slice * N_NODES + base;
  for (int i = tid; i < NQUART / 4; i += 1024)
    ((float4*)out)[i] = ((const float4*)bins)[i];
}

// dinv[n] = rsqrt(1 + sum_s partial[s][n])   (self-loop -> +1), float4-wide
__global__ void k_merge_deg(const float* __restrict__ partial,
                            float* __restrict__ dinv) {
  int i4 = blockIdx.x * 256 + threadIdx.x;          // float4 index
  if (i4 >= N_NODES / 4) return;
  float4 s = make_float4(1.f, 1.f, 1.f, 1.f);
#pragma unroll
  for (int sl = 0; sl < NSLICE; ++sl) {
    float4 p = ((const float4*)(partial + (size_t)sl * N_NODES))[i4];
    s.x += p.x; s.y += p.y; s.z += p.z; s.w += p.w;
  }
  float4 d = make_float4(rsqrtf(s.x), rsqrtf(s.y), rsqrtf(s.z), rsqrtf(s.w));
  ((float4*)dinv)[i4] = d;
}

// w[n] = dinv[n]*(sum_s partial[s][n] + dinv[n]);  also zero vacc+ticket
__global__ void k_merge_w(const float* __restrict__ partial,
                          const float* __restrict__ dinv,
                          float* __restrict__ w, float* __restrict__ vacc) {
  int i4 = blockIdx.x * 256 + threadIdx.x;
  int gid = i4;
  if (gid < 2 * HD) vacc[gid] = 0.f;
  if (gid == 2 * HD) ((unsigned*)vacc)[2 * HD] = 0u;   // ticket
  if (i4 >= N_NODES / 4) return;
  float4 s = make_float4(0.f, 0.f, 0.f, 0.f);
#pragma unroll
  for (int sl = 0; sl < NSLICE; ++sl) {
    float4 p = ((const float4*)(partial + (size_t)sl * N_NODES))[i4];
    s.x += p.x; s.y += p.y; s.z += p.z; s.w += p.w;
  }
  float4 d = ((const float4*)dinv)[i4];
  float4 o = make_float4(d.x * (s.x + d.x), d.y * (s.y + d.y),
                         d.z * (s.z + d.z), d.w * (s.w + d.w));
  ((float4*)w)[i4] = o;
}

// ---- main: vacc[b,h] = sum_n w[n]*relu(x[b,n,:]@W_feat+b_feat)[h];
//      last block (ticket) computes the whole head and writes out[2].
__global__ __launch_bounds__(256, 2) void k_main(
    const float* __restrict__ x, const float* __restrict__ Wf,
    const float* __restrict__ bfeat, const float* __restrict__ w,
    float* __restrict__ vacc,
    const float* __restrict__ Wg, const float* __restrict__ bg,
    const float* __restrict__ W1, const float* __restrict__ b1,
    const float* __restrict__ W2, const float* __restrict__ b2,
    float* __restrict__ out) {
  __shared__ __align__(16) short lW[32 * 64 * 8];   // 32 KB B-fragments
  __shared__ float red[4 * HD];                     // cross-wave reduce
  __shared__ float hs[2 * HD];                      // head scratch
  __shared__ bool amLast;
  const int tid = threadIdx.x;
  for (int c = tid; c < 2048; c += 256) {           // c = (kt*8+t)*64 + lane
    int lane = c & 63, t = (c >> 6) & 7, kt = c >> 9;
    int h = t * 16 + (lane & 15);
    int dbase = kt * 32 + (lane >> 4) * 8;
    short8 v;
#pragma unroll
    for (int j = 0; j < 8; ++j) v[j] = f2bf(Wf[(dbase + j) * HD + h]);
    *(short8*)&lW[c * 8] = v;
  }
  __syncthreads();

  const int lane = tid & 63;
  const int wave = tid >> 6;
  const int col  = lane & 15;
  const int quad = lane >> 4;
  const int b    = blockIdx.y;

  float bias[8];
#pragma unroll
  for (int t = 0; t < 8; ++t) bias[t] = bfeat[t * 16 + col];

  float pv[8];
#pragma unroll
  for (int t = 0; t < 8; ++t) pv[t] = 0.f;

  const float* xb = x + (size_t)b * N_NODES * HD;
  for (int tile = blockIdx.x * 4 + wave; tile < NTILES; tile += gridDim.x * 4) {
    const int n0 = tile * 16;
    const float* xr = xb + (size_t)(n0 + col) * HD + quad * 8;  // A row = col
    floatx4 w4 = *(const floatx4*)&w[n0 + quad * 4];  // D rows = quad*4 + r
    floatx4 acc[8] = {};
#pragma unroll
    for (int kt = 0; kt < 4; ++kt) {
      floatx4 xlo = *(const floatx4*)(xr + kt * 32);
      floatx4 xhi = *(const floatx4*)(xr + kt * 32 + 4);
      union { int4 i4; short8 s8; } a;
      a.i4.x = pk2(xlo[0], xlo[1]); a.i4.y = pk2(xlo[2], xlo[3]);
      a.i4.z = pk2(xhi[0], xhi[1]); a.i4.w = pk2(xhi[2], xhi[3]);
#pragma unroll
      for (int t = 0; t < 8; ++t) {
        short8 bf = *(const short8*)&lW[((kt * 8 + t) * 64 + lane) * 8];
        acc[t] = __builtin_amdgcn_mfma_f32_16x16x32_bf16(a.s8, bf, acc[t], 0, 0, 0);
      }
    }
#pragma unroll
    for (int t = 0; t < 8; ++t) {
#pragma unroll
      for (int r = 0; r < 4; ++r) {
        float y = acc[t][r] + bias[t];
        pv[t] += fmaxf(y, 0.f) * w4[r];
      }
    }
  }

  // cross-wave LDS reduce, one atomic per (b,h) per block
#pragma unroll
  for (int t = 0; t < 8; ++t) {
    float v = pv[t];
    v += __shfl_xor(v, 32, 64);
    v += __shfl_xor(v, 16, 64);
    if (quad == 0) red[wave * HD + t * 16 + col] = v;
  }
  __syncthreads();
  if (tid < HD) {
    float v = red[tid] + red[HD + tid] + red[2 * HD + tid] + red[3 * HD + tid];
    atomicAdd(&vacc[b * HD + tid], v);
  }
  // ---- ticket: last of gridDim.x*gridDim.y blocks runs the head ----
  __threadfence();
  if (tid == 0) {
    unsigned old = atomicAdd((unsigned*)&vacc[2 * HD], 1u);
    amLast = (old == gridDim.x * gridDim.y - 1);
  }
  __syncthreads();
  if (!amLast) return;

  // coherent readback of vacc into red[0..255]
  if (tid < 2 * HD) red[tid] = atomicAdd(&vacc[tid], 0.0f);
  __syncthreads();
  const int hb = tid >> 7, h = tid & 127;
  float acc = 0.f;
#pragma unroll 8
  for (int k = 0; k < HD; ++k) acc += red[hb * HD + k] * Wg[k * HD + h];
  hs[tid] = acc * (1.0f / N_NODES) + bg[h];          // pooled
  __syncthreads();
  acc = 0.f;
#pragma unroll 8
  for (int k = 0; k < HD; ++k) acc += hs[hb * HD + k] * W1[k * HD + h];
  float zv = fmaxf(acc + b1[h], 0.f);
  __syncthreads();
  hs[tid] = zv * W2[h];
  __syncthreads();
  if (tid < 2) {
    float sum = 0.f;
    for (int k = 0; k < HD; ++k) sum += hs[tid * HD + k];
    out[tid] = sum + b2[0];
  }
}

extern "C" void kernel_launch(void* const* d_in, const int* in_sizes, int n_in,
                              void* d_out, int out_size, void* d_ws, size_t ws_size,
                              hipStream_t stream) {
  const float* x  = (const float*)d_in[0];
  const int*   ei = (const int*)d_in[1];
  const float* Wf = (const float*)d_in[2];
  const float* bf = (const float*)d_in[3];
  const float* Wg = (const float*)d_in[4];
  const float* bg = (const float*)d_in[5];
  const float* W1 = (const float*)d_in[6];
  const float* b1 = (const float*)d_in[7];
  const float* W2 = (const float*)d_in[8];
  const float* b2 = (const float*)d_in[9];
  float* out = (float*)d_out;

  const int E = in_sizes[1] / 2;
  const int* src = ei;
  const int* dst = ei + E;
  const int perSlice = (E + NSLICE - 1) / NSLICE;

  char* ws = (char*)d_ws;
  const size_t partialB = (size_t)NSLICE * N_NODES * 4;          // 3.2 MB
  const size_t nodeB    = (N_NODES * 4 + 255) & ~(size_t)255;    // 200192 B
  float* partial = (float*)ws;
  float* dinv    = (float*)(ws + partialB);
  float* w       = (float*)(ws + partialB + nodeB);
  float* vacc    = (float*)(ws + partialB + 2 * nodeB);  // 256 f32 + ticket

  k_scatter<false><<<NSLICE * 4, 1024, 0, stream>>>(dst, nullptr, nullptr,
                                                    partial, E, perSlice);
  k_merge_deg<<<(N_NODES / 4 + 255) / 256, 256, 0, stream>>>(partial, dinv);
  k_scatter<true><<<NSLICE * 4, 1024, 0, stream>>>(src, dst, dinv,
                                                   partial, E, perSlice);
  k_merge_w<<<(N_NODES / 4 + 255) / 256, 256, 0, stream>>>(partial, dinv, w, vacc);
  dim3 grid(256, 2);
  k_main<<<grid, 256, 0, stream>>>(x, Wf, bf, w, vacc,
                                   Wg, bg, W1, b1, W2, b2, out);
  (void)n_in; (void)out_size; (void)ws_size;
}

// Round 4
// 178.074 us; speedup vs baseline: 1.1425x; 1.1425x over previous
//
#include <hip/hip_runtime.h>
#include <hip/hip_bf16.h>

#define N_NODES 50000
#define HD 128
#define NTILES (N_NODES / 16)   // 3125, exact
#define NSLICE 16               // edge slices for privatized scatter
#define NQUART 12500            // nodes per LDS quarter (50 KB f32 bins)

using short8  = __attribute__((ext_vector_type(8))) short;   // 8 x bf16 bits
using floatx4 = __attribute__((ext_vector_type(4))) float;

__device__ __forceinline__ int pk2(float a, float b) {
#if __has_builtin(__builtin_amdgcn_cvt_pk_bf16_f32)
  typedef __bf16 bf2 __attribute__((ext_vector_type(2)));
  union { bf2 v; int i; } u;
  u.v = __builtin_amdgcn_cvt_pk_bf16_f32(a, b);
  return u.i;
#else
  union { float f; unsigned u; } x, y;
  x.f = a; y.f = b;
  unsigned lo = (x.u + 0x7fffu + ((x.u >> 16) & 1u)) >> 16;
  unsigned hi = (y.u + 0x7fffu + ((y.u >> 16) & 1u)) >> 16;
  return (int)(lo | (hi << 16));
#endif
}

__device__ __forceinline__ short f2bf(float f) {
  union { float fp; unsigned u; } un; un.fp = f;
  unsigned u = un.u + 0x7fffu + ((un.u >> 16) & 1u);   // RNE
  return (short)(u >> 16);
}

// =====================  edge phase (LDS-privatized, no device atomics) ======
// grid = 64 blocks x 1024.  slice = blk&15 (XCD-swizzled so the 4 quarter-
// blocks of a slice share an XCD's L2), quarter = blk>>4.
template <bool GATHER>
__global__ __launch_bounds__(1024) void k_scatter(
    const int* __restrict__ keys, const int* __restrict__ other,
    const float* __restrict__ dinv, float* __restrict__ partial,
    int E, int perSlice) {
  __shared__ __align__(16) float bins[NQUART];
  const int tid = threadIdx.x;
  for (int i = tid; i < NQUART / 4; i += 1024)
    ((float4*)bins)[i] = make_float4(0.f, 0.f, 0.f, 0.f);
  __syncthreads();

  const int slice = blockIdx.x & (NSLICE - 1);
  const int base  = (blockIdx.x >> 4) * NQUART;
  const int e0 = slice * perSlice;
  const int e1 = min(e0 + perSlice, E);
  for (int e = e0 + tid; e < e1; e += 1024) {
    int k = keys[e];
    if ((unsigned)(k - base) < (unsigned)NQUART) {
      float v = GATHER ? dinv[other[e]] : 1.0f;
      atomicAdd(&bins[k - base], v);           // ds_add_f32, LDS-local
    }
  }
  __syncthreads();

  float* out = partial + (size_t)slice * N_NODES + base;
  for (int i = tid; i < NQUART / 4; i += 1024)
    ((float4*)out)[i] = ((const float4*)bins)[i];
}

// dinv[n] = rsqrt(1 + sum_s partial[s][n])   (self-loop -> +1), float4-wide
__global__ void k_merge_deg(const float* __restrict__ partial,
                            float* __restrict__ dinv) {
  int i4 = blockIdx.x * 256 + threadIdx.x;          // float4 index
  if (i4 >= N_NODES / 4) return;
  float4 s = make_float4(1.f, 1.f, 1.f, 1.f);
#pragma unroll
  for (int sl = 0; sl < NSLICE; ++sl) {
    float4 p = ((const float4*)(partial + (size_t)sl * N_NODES))[i4];
    s.x += p.x; s.y += p.y; s.z += p.z; s.w += p.w;
  }
  float4 d = make_float4(rsqrtf(s.x), rsqrtf(s.y), rsqrtf(s.z), rsqrtf(s.w));
  ((float4*)dinv)[i4] = d;
}

// w[n] = dinv[n]*(sum_s partial[s][n] + dinv[n]);  also zero vacc
__global__ void k_merge_w(const float* __restrict__ partial,
                          const float* __restrict__ dinv,
                          float* __restrict__ w, float* __restrict__ vacc) {
  int i4 = blockIdx.x * 256 + threadIdx.x;
  if (i4 < 2 * HD) vacc[i4] = 0.f;
  if (i4 >= N_NODES / 4) return;
  float4 s = make_float4(0.f, 0.f, 0.f, 0.f);
#pragma unroll
  for (int sl = 0; sl < NSLICE; ++sl) {
    float4 p = ((const float4*)(partial + (size_t)sl * N_NODES))[i4];
    s.x += p.x; s.y += p.y; s.z += p.z; s.w += p.w;
  }
  float4 d = ((const float4*)dinv)[i4];
  float4 o = make_float4(d.x * (s.x + d.x), d.y * (s.y + d.y),
                         d.z * (s.z + d.z), d.w * (s.w + d.w));
  ((float4*)w)[i4] = o;
}

// ---- main: vacc[b,h] = sum_n w[n] * relu(x[b,n,:] @ W_feat + b_feat)[h] ----
__global__ __launch_bounds__(256, 2) void k_main(
    const float* __restrict__ x, const float* __restrict__ Wf,
    const float* __restrict__ bfeat, const float* __restrict__ w,
    float* __restrict__ vacc) {
  // B-fragments of W_feat, pre-swizzled: frag (kt,t), lane-contiguous 16B
  __shared__ __align__(16) short lW[32 * 64 * 8];   // 32 KB
  const int tid = threadIdx.x;
  for (int c = tid; c < 2048; c += 256) {           // c = (kt*8+t)*64 + lane
    int lane = c & 63, t = (c >> 6) & 7, kt = c >> 9;
    int h = t * 16 + (lane & 15);
    int dbase = kt * 32 + (lane >> 4) * 8;
    short8 v;
#pragma unroll
    for (int j = 0; j < 8; ++j) v[j] = f2bf(Wf[(dbase + j) * HD + h]);
    *(short8*)&lW[c * 8] = v;
  }
  __syncthreads();

  const int lane = tid & 63;
  const int wave = tid >> 6;
  const int col  = lane & 15;
  const int quad = lane >> 4;
  const int b    = blockIdx.y;

  float bias[8];
#pragma unroll
  for (int t = 0; t < 8; ++t) bias[t] = bfeat[t * 16 + col];

  float pv[8];
#pragma unroll
  for (int t = 0; t < 8; ++t) pv[t] = 0.f;

  const float* xb = x + (size_t)b * N_NODES * HD;
  for (int tile = blockIdx.x * 4 + wave; tile < NTILES; tile += gridDim.x * 4) {
    const int n0 = tile * 16;
    const float* xr = xb + (size_t)(n0 + col) * HD + quad * 8;  // A row = col
    floatx4 w4 = *(const floatx4*)&w[n0 + quad * 4];  // D rows = quad*4 + r
    floatx4 acc[8] = {};
#pragma unroll
    for (int kt = 0; kt < 4; ++kt) {
      floatx4 xlo = *(const floatx4*)(xr + kt * 32);
      floatx4 xhi = *(const floatx4*)(xr + kt * 32 + 4);
      union { int4 i4; short8 s8; } a;
      a.i4.x = pk2(xlo[0], xlo[1]); a.i4.y = pk2(xlo[2], xlo[3]);
      a.i4.z = pk2(xhi[0], xhi[1]); a.i4.w = pk2(xhi[2], xhi[3]);
#pragma unroll
      for (int t = 0; t < 8; ++t) {
        short8 bf = *(const short8*)&lW[((kt * 8 + t) * 64 + lane) * 8];
        acc[t] = __builtin_amdgcn_mfma_f32_16x16x32_bf16(a.s8, bf, acc[t], 0, 0, 0);
      }
    }
#pragma unroll
    for (int t = 0; t < 8; ++t) {
#pragma unroll
      for (int r = 0; r < 4; ++r) {
        float y = acc[t][r] + bias[t];
        pv[t] += fmaxf(y, 0.f) * w4[r];
      }
    }
  }

  // cross-wave LDS reduce, then ONE atomic per (b,h) per block
  __syncthreads();                     // all lW reads done; reuse as scratch
  float* red = (float*)lW;             // need 4*128 floats
#pragma unroll
  for (int t = 0; t < 8; ++t) {
    float v = pv[t];
    v += __shfl_xor(v, 32, 64);
    v += __shfl_xor(v, 16, 64);
    if (quad == 0) red[wave * HD + t * 16 + col] = v;
  }
  __syncthreads();
  if (tid < HD) {
    float v = red[tid] + red[HD + tid] + red[2 * HD + tid] + red[3 * HD + tid];
    atomicAdd(&vacc[b * HD + tid], v);
  }
}

// ---- tiny head: pooled = (v/N)@W_gcn + b_gcn; z = relu(pooled@W_fc1+b1); out = z@W_fc2+b2
__global__ void k_final(const float* __restrict__ vacc, const float* __restrict__ Wg,
                        const float* __restrict__ bg, const float* __restrict__ W1,
                        const float* __restrict__ b1, const float* __restrict__ W2,
                        const float* __restrict__ b2, float* __restrict__ out) {
  __shared__ float pooled[2][HD];
  __shared__ float z[2][HD];
  __shared__ float red[256];
  const int tid = threadIdx.x;
  const int b = tid >> 7, h = tid & 127;
  float acc = 0.f;
#pragma unroll 8
  for (int k = 0; k < HD; ++k) acc += vacc[b * HD + k] * Wg[k * HD + h];
  pooled[b][h] = acc * (1.0f / N_NODES) + bg[h];
  __syncthreads();
  acc = 0.f;
#pragma unroll 8
  for (int k = 0; k < HD; ++k) acc += pooled[b][k] * W1[k * HD + h];
  z[b][h] = fmaxf(acc + b1[h], 0.f);
  __syncthreads();
  red[tid] = z[b][h] * W2[h];
  __syncthreads();
  if (tid < 2) {
    float sum = 0.f;
    for (int k = 0; k < HD; ++k) sum += red[tid * HD + k];
    out[tid] = sum + b2[0];
  }
}

extern "C" void kernel_launch(void* const* d_in, const int* in_sizes, int n_in,
                              void* d_out, int out_size, void* d_ws, size_t ws_size,
                              hipStream_t stream) {
  const float* x  = (const float*)d_in[0];
  const int*   ei = (const int*)d_in[1];
  const float* Wf = (const float*)d_in[2];
  const float* bf = (const float*)d_in[3];
  const float* Wg = (const float*)d_in[4];
  const float* bg = (const float*)d_in[5];
  const float* W1 = (const float*)d_in[6];
  const float* b1 = (const float*)d_in[7];
  const float* W2 = (const float*)d_in[8];
  const float* b2 = (const float*)d_in[9];
  float* out = (float*)d_out;

  const int E = in_sizes[1] / 2;
  const int* src = ei;
  const int* dst = ei + E;
  const int perSlice = (E + NSLICE - 1) / NSLICE;

  char* ws = (char*)d_ws;
  const size_t partialB = (size_t)NSLICE * N_NODES * 4;          // 3.2 MB
  const size_t nodeB    = (N_NODES * 4 + 255) & ~(size_t)255;    // 200192 B
  float* partial = (float*)ws;
  float* dinv    = (float*)(ws + partialB);
  float* w       = (float*)(ws + partialB + nodeB);
  float* vacc    = (float*)(ws + partialB + 2 * nodeB);

  k_scatter<false><<<NSLICE * 4, 1024, 0, stream>>>(dst, nullptr, nullptr,
                                                    partial, E, perSlice);
  k_merge_deg<<<(N_NODES / 4 + 255) / 256, 256, 0, stream>>>(partial, dinv);
  k_scatter<true><<<NSLICE * 4, 1024, 0, stream>>>(src, dst, dinv,
                                                   partial, E, perSlice);
  k_merge_w<<<(N_NODES / 4 + 255) / 256, 256, 0, stream>>>(partial, dinv, w, vacc);
  dim3 grid(256, 2);
  k_main<<<grid, 256, 0, stream>>>(x, Wf, bf, w, vacc);
  k_final<<<1, 256, 0, stream>>>(vacc, Wg, bg, W1, b1, W2, b2, out);
  (void)n_in; (void)out_size; (void)ws_size;
}

// Round 5
// 158.054 us; speedup vs baseline: 1.2872x; 1.1267x over previous
//
#include <hip/hip_runtime.h>
#include <hip/hip_bf16.h>

#define N_NODES 50000
#define HD 128
#define NTILES (N_NODES / 16)   // 3125, exact
#define NSLICE 64               // edge slices for privatized scatter
#define NQUART 12500            // nodes per LDS quarter (50 KB f32 bins)

using short8  = __attribute__((ext_vector_type(8))) short;   // 8 x bf16 bits
using floatx4 = __attribute__((ext_vector_type(4))) float;

__device__ __forceinline__ int pk2(float a, float b) {
#if __has_builtin(__builtin_amdgcn_cvt_pk_bf16_f32)
  typedef __bf16 bf2 __attribute__((ext_vector_type(2)));
  union { bf2 v; int i; } u;
  u.v = __builtin_amdgcn_cvt_pk_bf16_f32(a, b);
  return u.i;
#else
  union { float f; unsigned u; } x, y;
  x.f = a; y.f = b;
  unsigned lo = (x.u + 0x7fffu + ((x.u >> 16) & 1u)) >> 16;
  unsigned hi = (y.u + 0x7fffu + ((y.u >> 16) & 1u)) >> 16;
  return (int)(lo | (hi << 16));
#endif
}

__device__ __forceinline__ short f2bf(float f) {
  union { float fp; unsigned u; } un; un.fp = f;
  unsigned u = un.u + 0x7fffu + ((un.u >> 16) & 1u);   // RNE
  return (short)(u >> 16);
}

// =====================  edge phase (LDS-privatized, no device atomics) ======
// 256 blocks x 1024: slice = blk&63 (quarters of a slice share an XCD),
// quarter = blk>>6.  int4 edge loads give 4-8 outstanding loads/lane.
template <bool GATHER>
__global__ __launch_bounds__(1024) void k_scatter(
    const int* __restrict__ keys, const int* __restrict__ other,
    const float* __restrict__ dinv, float* __restrict__ partial,
    int E, int perSlice) {
  __shared__ __align__(16) float bins[NQUART];
  const int tid = threadIdx.x;
  for (int i = tid; i < NQUART / 4; i += 1024)
    ((float4*)bins)[i] = make_float4(0.f, 0.f, 0.f, 0.f);
  __syncthreads();

  const int slice = blockIdx.x & (NSLICE - 1);
  const int base  = (blockIdx.x >> 6) * NQUART;
  const int e0 = slice * perSlice;
  const int e1 = min(e0 + perSlice, E);

  int nv = 0;
  if ((e0 & 3) == 0) {                       // 16B-aligned vector path
    nv = (e1 - e0) >> 2;
    const int4* k4 = (const int4*)(keys + e0);
    const int4* o4 = (const int4*)(other + e0);
    for (int i = tid; i < nv; i += 1024) {
      int4 k = k4[i];
      float4 v = make_float4(1.f, 1.f, 1.f, 1.f);
      if (GATHER) {
        int4 o = o4[i];
        v.x = dinv[o.x]; v.y = dinv[o.y]; v.z = dinv[o.z]; v.w = dinv[o.w];
      }
      if ((unsigned)(k.x - base) < (unsigned)NQUART) atomicAdd(&bins[k.x - base], v.x);
      if ((unsigned)(k.y - base) < (unsigned)NQUART) atomicAdd(&bins[k.y - base], v.y);
      if ((unsigned)(k.z - base) < (unsigned)NQUART) atomicAdd(&bins[k.z - base], v.z);
      if ((unsigned)(k.w - base) < (unsigned)NQUART) atomicAdd(&bins[k.w - base], v.w);
    }
  }
  for (int e = e0 + (nv << 2) + tid; e < e1; e += 1024) {   // tail / unaligned
    int k = keys[e];
    if ((unsigned)(k - base) < (unsigned)NQUART) {
      float v = GATHER ? dinv[other[e]] : 1.0f;
      atomicAdd(&bins[k - base], v);
    }
  }
  __syncthreads();

  float* out = partial + (size_t)slice * N_NODES + base;
  for (int i = tid; i < NQUART / 4; i += 1024)
    ((float4*)out)[i] = ((const float4*)bins)[i];
}

// dinv[n] = rsqrt(1 + sum_s partial[s][n])   (self-loop -> +1), float4-wide
__global__ void k_merge_deg(const float* __restrict__ partial,
                            float* __restrict__ dinv) {
  int i4 = blockIdx.x * 256 + threadIdx.x;          // float4 index
  if (i4 >= N_NODES / 4) return;
  float4 s = make_float4(1.f, 1.f, 1.f, 1.f);
#pragma unroll 16
  for (int sl = 0; sl < NSLICE; ++sl) {
    float4 p = ((const float4*)(partial + (size_t)sl * N_NODES))[i4];
    s.x += p.x; s.y += p.y; s.z += p.z; s.w += p.w;
  }
  float4 d = make_float4(rsqrtf(s.x), rsqrtf(s.y), rsqrtf(s.z), rsqrtf(s.w));
  ((float4*)dinv)[i4] = d;
}

// w[n] = dinv[n]*(sum_s partial[s][n] + dinv[n]);  also zero vacc
__global__ void k_merge_w(const float* __restrict__ partial,
                          const float* __restrict__ dinv,
                          float* __restrict__ w, float* __restrict__ vacc) {
  int i4 = blockIdx.x * 256 + threadIdx.x;
  if (i4 < 2 * HD) vacc[i4] = 0.f;
  if (i4 >= N_NODES / 4) return;
  float4 s = make_float4(0.f, 0.f, 0.f, 0.f);
#pragma unroll 16
  for (int sl = 0; sl < NSLICE; ++sl) {
    float4 p = ((const float4*)(partial + (size_t)sl * N_NODES))[i4];
    s.x += p.x; s.y += p.y; s.z += p.z; s.w += p.w;
  }
  float4 d = ((const float4*)dinv)[i4];
  float4 o = make_float4(d.x * (s.x + d.x), d.y * (s.y + d.y),
                         d.z * (s.z + d.z), d.w * (s.w + d.w));
  ((float4*)w)[i4] = o;
}

// ---- main: vacc[b,h] = sum_n w[n] * relu(x[b,n,:] @ W_feat + b_feat)[h] ----
__global__ __launch_bounds__(256, 2) void k_main(
    const float* __restrict__ x, const float* __restrict__ Wf,
    const float* __restrict__ bfeat, const float* __restrict__ w,
    float* __restrict__ vacc) {
  // B-fragments of W_feat, pre-swizzled: frag (kt,t), lane-contiguous 16B
  __shared__ __align__(16) short lW[32 * 64 * 8];   // 32 KB
  const int tid = threadIdx.x;
  for (int c = tid; c < 2048; c += 256) {           // c = (kt*8+t)*64 + lane
    int lane = c & 63, t = (c >> 6) & 7, kt = c >> 9;
    int h = t * 16 + (lane & 15);
    int dbase = kt * 32 + (lane >> 4) * 8;
    short8 v;
#pragma unroll
    for (int j = 0; j < 8; ++j) v[j] = f2bf(Wf[(dbase + j) * HD + h]);
    *(short8*)&lW[c * 8] = v;
  }
  __syncthreads();

  const int lane = tid & 63;
  const int wave = tid >> 6;
  const int col  = lane & 15;
  const int quad = lane >> 4;
  const int b    = blockIdx.y;

  float bias[8];
#pragma unroll
  for (int t = 0; t < 8; ++t) bias[t] = bfeat[t * 16 + col];

  float pv[8];
#pragma unroll
  for (int t = 0; t < 8; ++t) pv[t] = 0.f;

  const float* xb = x + (size_t)b * N_NODES * HD;
  for (int tile = blockIdx.x * 4 + wave; tile < NTILES; tile += gridDim.x * 4) {
    const int n0 = tile * 16;
    const float* xr = xb + (size_t)(n0 + col) * HD + quad * 8;  // A row = col
    floatx4 w4 = *(const floatx4*)&w[n0 + quad * 4];  // D rows = quad*4 + r
    floatx4 acc[8] = {};
#pragma unroll
    for (int kt = 0; kt < 4; ++kt) {
      floatx4 xlo = *(const floatx4*)(xr + kt * 32);
      floatx4 xhi = *(const floatx4*)(xr + kt * 32 + 4);
      union { int4 i4; short8 s8; } a;
      a.i4.x = pk2(xlo[0], xlo[1]); a.i4.y = pk2(xlo[2], xlo[3]);
      a.i4.z = pk2(xhi[0], xhi[1]); a.i4.w = pk2(xhi[2], xhi[3]);
#pragma unroll
      for (int t = 0; t < 8; ++t) {
        short8 bf = *(const short8*)&lW[((kt * 8 + t) * 64 + lane) * 8];
        acc[t] = __builtin_amdgcn_mfma_f32_16x16x32_bf16(a.s8, bf, acc[t], 0, 0, 0);
      }
    }
#pragma unroll
    for (int t = 0; t < 8; ++t) {
#pragma unroll
      for (int r = 0; r < 4; ++r) {
        float y = acc[t][r] + bias[t];
        pv[t] += fmaxf(y, 0.f) * w4[r];
      }
    }
  }

  // cross-wave LDS reduce, then ONE atomic per (b,h) per block
  __syncthreads();                     // all lW reads done; reuse as scratch
  float* red = (float*)lW;             // need 4*128 floats
#pragma unroll
  for (int t = 0; t < 8; ++t) {
    float v = pv[t];
    v += __shfl_xor(v, 32, 64);
    v += __shfl_xor(v, 16, 64);
    if (quad == 0) red[wave * HD + t * 16 + col] = v;
  }
  __syncthreads();
  if (tid < HD) {
    float v = red[tid] + red[HD + tid] + red[2 * HD + tid] + red[3 * HD + tid];
    atomicAdd(&vacc[b * HD + tid], v);
  }
}

// ---- tiny head: pooled = (v/N)@W_gcn + b_gcn; z = relu(pooled@W_fc1+b1); out = z@W_fc2+b2
__global__ void k_final(const float* __restrict__ vacc, const float* __restrict__ Wg,
                        const float* __restrict__ bg, const float* __restrict__ W1,
                        const float* __restrict__ b1, const float* __restrict__ W2,
                        const float* __restrict__ b2, float* __restrict__ out) {
  __shared__ float pooled[2][HD];
  __shared__ float z[2][HD];
  __shared__ float red[256];
  const int tid = threadIdx.x;
  const int b = tid >> 7, h = tid & 127;
  float acc = 0.f;
#pragma unroll 8
  for (int k = 0; k < HD; ++k) acc += vacc[b * HD + k] * Wg[k * HD + h];
  pooled[b][h] = acc * (1.0f / N_NODES) + bg[h];
  __syncthreads();
  acc = 0.f;
#pragma unroll 8
  for (int k = 0; k < HD; ++k) acc += pooled[b][k] * W1[k * HD + h];
  z[b][h] = fmaxf(acc + b1[h], 0.f);
  __syncthreads();
  red[tid] = z[b][h] * W2[h];
  __syncthreads();
  if (tid < 2) {
    float sum = 0.f;
    for (int k = 0; k < HD; ++k) sum += red[tid * HD + k];
    out[tid] = sum + b2[0];
  }
}

extern "C" void kernel_launch(void* const* d_in, const int* in_sizes, int n_in,
                              void* d_out, int out_size, void* d_ws, size_t ws_size,
                              hipStream_t stream) {
  const float* x  = (const float*)d_in[0];
  const int*   ei = (const int*)d_in[1];
  const float* Wf = (const float*)d_in[2];
  const float* bf = (const float*)d_in[3];
  const float* Wg = (const float*)d_in[4];
  const float* bg = (const float*)d_in[5];
  const float* W1 = (const float*)d_in[6];
  const float* b1 = (const float*)d_in[7];
  const float* W2 = (const float*)d_in[8];
  const float* b2 = (const float*)d_in[9];
  float* out = (float*)d_out;

  const int E = in_sizes[1] / 2;
  const int* src = ei;
  const int* dst = ei + E;
  const int perSlice = (E + NSLICE - 1) / NSLICE;

  char* ws = (char*)d_ws;
  const size_t partialB = (size_t)NSLICE * N_NODES * 4;          // 12.8 MB
  const size_t nodeB    = (N_NODES * 4 + 255) & ~(size_t)255;    // 200192 B
  float* partial = (float*)ws;
  float* dinv    = (float*)(ws + partialB);
  float* w       = (float*)(ws + partialB + nodeB);
  float* vacc    = (float*)(ws + partialB + 2 * nodeB);

  k_scatter<false><<<NSLICE * 4, 1024, 0, stream>>>(dst, dst, nullptr,
                                                    partial, E, perSlice);
  k_merge_deg<<<(N_NODES / 4 + 255) / 256, 256, 0, stream>>>(partial, dinv);
  k_scatter<true><<<NSLICE * 4, 1024, 0, stream>>>(src, dst, dinv,
                                                   partial, E, perSlice);
  k_merge_w<<<(N_NODES / 4 + 255) / 256, 256, 0, stream>>>(partial, dinv, w, vacc);
  dim3 grid(256, 2);
  k_main<<<grid, 256, 0, stream>>>(x, Wf, bf, w, vacc);
  k_final<<<1, 256, 0, stream>>>(vacc, Wg, bg, W1, b1, W2, b2, out);
  (void)n_in; (void)out_size; (void)ws_size;
}